// Round 8
// baseline (105.583 us; speedup 1.0000x reference)
//
#include <hip/hip_runtime.h>
#include <hip/hip_bf16.h>
#include <math.h>

#define B 64
#define L 64
#define NPT 127
#define D 128
#define VOCAB 30000
#define LABELS 30
#define SPLIT 4
#define KP 132    // padded LDS row stride (floats) for K/V tiles in k2 (16B-aligned)
#define EP 132    // padded row stride (floats), bank-spread for 8-row broadcast reads
#define WCS 136   // wcT row stride in ushorts (272B: 16B-aligned)

typedef __attribute__((ext_vector_type(8))) short bf16x8;
typedef __attribute__((ext_vector_type(4))) float f32x4;

__device__ __forceinline__ float bfhi(unsigned int u) {
  unsigned int x = u & 0xffff0000u;
  return __builtin_bit_cast(float, x);
}
__device__ __forceinline__ float bflo(unsigned int u) {
  unsigned int x = u << 16;
  return __builtin_bit_cast(float, x);
}
__device__ __forceinline__ unsigned short f2bf(float f) {
  __hip_bfloat16 h = __float2bfloat16(f);  // RNE
  return __builtin_bit_cast(unsigned short, h);
}

// ---------------------------------------------------------------------------
// K0 (MFMA): T[v][e] = bf16( sum_d emb[v][d]*Wc[d][e] + bc[e] )
// Wc^T staged in LDS bf16 with coalesced global reads.
// ---------------------------------------------------------------------------
__global__ __launch_bounds__(256) void k0_embWc(const float* __restrict__ emb,
                                                const float* __restrict__ Wc,
                                                const float* __restrict__ bc,
                                                __hip_bfloat16* __restrict__ T) {
  __shared__ unsigned short wcT[D * WCS];  // Wc^T bf16: wcT[e*WCS + d], ~34KB
  const int t = threadIdx.x;
  for (int i = t; i < D * D / 4; i += 256) {
    const int d = i >> 5;            // row of Wc
    const int e0 = (i & 31) * 4;     // 4 consecutive cols (lane-fast)
    float4 wv = *(const float4*)&Wc[d * D + e0];
    wcT[(e0 + 0) * WCS + d] = f2bf(wv.x);
    wcT[(e0 + 1) * WCS + d] = f2bf(wv.y);
    wcT[(e0 + 2) * WCS + d] = f2bf(wv.z);
    wcT[(e0 + 3) * WCS + d] = f2bf(wv.w);
  }
  __syncthreads();
  const int w = t >> 6, lane = t & 63;
  const int m = lane & 15;       // A-row / B-col within tile
  const int kg = lane >> 4;      // k-group 0..3
  int arow = blockIdx.x * 64 + w * 16 + m;
  if (arow >= VOCAB) arow = VOCAB - 1;  // clamp reads; stores guarded below
  const float* ap = emb + (size_t)arow * D + kg * 8;
  bf16x8 afrag[4];
#pragma unroll
  for (int kc = 0; kc < 4; ++kc) {
    float4 lo = *(const float4*)(ap + kc * 32);
    float4 hi = *(const float4*)(ap + kc * 32 + 4);
    union { bf16x8 v; unsigned short s[8]; } u;
    u.s[0] = f2bf(lo.x); u.s[1] = f2bf(lo.y); u.s[2] = f2bf(lo.z); u.s[3] = f2bf(lo.w);
    u.s[4] = f2bf(hi.x); u.s[5] = f2bf(hi.y); u.s[6] = f2bf(hi.z); u.s[7] = f2bf(hi.w);
    afrag[kc] = u.v;
  }
  const int grow0 = blockIdx.x * 64 + w * 16 + kg * 4;
#pragma unroll
  for (int ct = 0; ct < 8; ++ct) {
    const int col = ct * 16 + m;
    f32x4 acc = {0.f, 0.f, 0.f, 0.f};
#pragma unroll
    for (int kc = 0; kc < 4; ++kc) {
      bf16x8 bfrag = *(const bf16x8*)&wcT[col * WCS + kc * 32 + kg * 8];
      acc = __builtin_amdgcn_mfma_f32_16x16x32_bf16(afrag[kc], bfrag, acc, 0, 0, 0);
    }
    const float bcv = bc[col];
#pragma unroll
    for (int r = 0; r < 4; ++r) {
      const int grow = grow0 + r;
      if (grow < VOCAB)
        T[(size_t)grow * D + col] = __float2bfloat16(acc[r] + bcv);
    }
  }
}

// ---------------------------------------------------------------------------
// K1 (fused tree + qkv): one WAVE per (b,l) row for the tree (R5 register-
// stack streaming, tokens via wave-uniform scalar loads), enc rows to LDS;
// then phase 2: wave w computes output dims [16w,16w+16) of q/k/v for all
// 8 rows (W read exactly once per block).
// ---------------------------------------------------------------------------
__global__ __launch_bounds__(512) void k1_tree_qkv(
    const int* __restrict__ tokens, const __hip_bfloat16* __restrict__ T,
    const float* __restrict__ Wq, const float* __restrict__ Wk,
    const float* __restrict__ Wv, float* __restrict__ qb,
    float* __restrict__ kb, float* __restrict__ vb) {
  __shared__ float sEnc[8][EP];
  const int t = threadIdx.x;
  const int w = __builtin_amdgcn_readfirstlane(t >> 6);  // wave id, SGPR
  const int lane = t & 63;
  const int row = blockIdx.x * 8 + w;                    // wave-uniform
  const int* __restrict__ tokrow = tokens + (size_t)row * NPT;
  const unsigned* Tp = (const unsigned*)T;  // one u32 = dim pair; row = 64 u32
  float m0 = -1e30f, m1 = -1e30f;
  float stk0[6], stk1[6];
#pragma unroll
  for (int li = 0; li < 64; ++li) {
    int tokl = tokrow[63 + li];               // scalar load (uniform addr)
    unsigned u = Tp[(size_t)tokl * 64 + lane];
    float cur0 = bflo(u), cur1 = bfhi(u);
    m0 = fmaxf(m0, cur0);
    m1 = fmaxf(m1, cur1);
    int x = li;
#pragma unroll
    for (int h = 0; h < 6; ++h) {
      if (!(x & 1)) break;
      int pn = ((64 + li) >> (h + 1)) - 1;
      int tokp = tokrow[pn];                  // scalar load (uniform addr)
      unsigned up = Tp[(size_t)tokp * 64 + lane];
      cur0 = stk0[h] + cur0 + bflo(up);
      cur1 = stk1[h] + cur1 + bfhi(up);
      m0 = fmaxf(m0, cur0);
      m1 = fmaxf(m1, cur1);
      x >>= 1;
    }
    if (li != 63) {
      int h2 = 0, y = li;
      while (y & 1) { ++h2; y >>= 1; }
      stk0[h2] = cur0;
      stk1[h2] = cur1;
    }
  }
  sEnc[w][2 * lane] = fmaxf(m0, 0.0f);
  sEnc[w][2 * lane + 1] = fmaxf(m1, 0.0f);
  __syncthreads();
  // phase 2: wave w -> dims [16w, 16w+16); lane = (row<<3) | dimpair
  const int prow = lane >> 3;               // 0..7
  const int d0 = w * 16 + (lane & 7) * 2;
  float aq0 = 0, aq1 = 0, ak0 = 0, ak1 = 0, av0 = 0, av1 = 0;
#pragma unroll 8
  for (int k = 0; k < D; ++k) {
    float e = sEnc[prow][k];                // 8 distinct banks, broadcast x8
    float2 wq = *(const float2*)&Wq[k * D + d0];
    float2 wk = *(const float2*)&Wk[k * D + d0];
    float2 wv = *(const float2*)&Wv[k * D + d0];
    aq0 += e * wq.x; aq1 += e * wq.y;
    ak0 += e * wk.x; ak1 += e * wk.y;
    av0 += e * wv.x; av1 += e * wv.y;
  }
  const size_t orow = (size_t)(blockIdx.x * 8 + prow) * D + d0;
  *(float2*)&qb[orow] = make_float2(aq0, aq1);
  *(float2*)&kb[orow] = make_float2(ak0, ak1);
  *(float2*)&vb[orow] = make_float2(av0, av1);
}

// ---------------------------------------------------------------------------
// K2: attention for one (batch, split of 16 q-rows). Writes pre-Wo rows.
// ---------------------------------------------------------------------------
__global__ __launch_bounds__(512) void k2_attn(
    const float* __restrict__ qb, const float* __restrict__ kb,
    const float* __restrict__ vb, const int* __restrict__ mask,
    float* __restrict__ ob) {
  __shared__ float sK[L * KP];
  __shared__ float sV[L * KP];
  __shared__ float sQ[8][D];
  const int t = threadIdx.x;
  const int w = t >> 6, lane = t & 63;
  const int b = blockIdx.x / SPLIT;
  const int sp = blockIdx.x % SPLIT;
  for (int i = t * 4; i < L * D; i += 512 * 4) {
    int r = i >> 7, c = i & 127;
    float4 kv = *(const float4*)&kb[(size_t)(b * L + r) * D + c];
    float4 vv = *(const float4*)&vb[(size_t)(b * L + r) * D + c];
    *(float4*)&sK[r * KP + c] = kv;
    *(float4*)&sV[r * KP + c] = vv;
  }
  __syncthreads();
#pragma unroll
  for (int it = 0; it < 2; ++it) {
    const int r = sp * 16 + w * 2 + it;
    float2 qv = *(const float2*)&qb[(size_t)(b * L + r) * D + lane * 2];
    sQ[w][lane * 2] = qv.x;
    sQ[w][lane * 2 + 1] = qv.y;
    float sc = 0.f;
    const float4* kr = (const float4*)&sK[lane * KP];
    const float4* qr = (const float4*)&sQ[w][0];
#pragma unroll 8
    for (int k4 = 0; k4 < 32; ++k4) {
      float4 kv = kr[k4];
      float4 q4 = qr[k4];
      sc += q4.x * kv.x + q4.y * kv.y + q4.z * kv.z + q4.w * kv.w;
    }
    sc *= 0.08838834764831845f;
    if (mask[((size_t)b * L + r) * L + lane] <= 0) sc = -1e9f;
    float mx = sc;
#pragma unroll
    for (int off = 32; off >= 1; off >>= 1) mx = fmaxf(mx, __shfl_xor(mx, off));
    float ex = __expf(sc - mx);
    float sm = ex;
#pragma unroll
    for (int off = 32; off >= 1; off >>= 1) sm += __shfl_xor(sm, off);
    float a = ex / sm;
    float o0 = 0.f, o1 = 0.f;
#pragma unroll
    for (int j = 0; j < L; ++j) {
      float aj = __shfl(a, j);
      o0 += aj * sV[j * KP + lane];
      o1 += aj * sV[j * KP + lane + 64];
    }
    ob[(size_t)(b * L + r) * D + lane] = o0;
    ob[(size_t)(b * L + r) * D + lane + 64] = o1;
  }
}

// ---------------------------------------------------------------------------
// K23: per batch (64 blocks, 512 threads): out2 = ob@Wo in LDS,
// pooled max over rows, logits -> out.
// ---------------------------------------------------------------------------
__global__ __launch_bounds__(512) void k23_proj_pool(
    const float* __restrict__ ob, const float* __restrict__ Wo,
    const float* __restrict__ Wl, const float* __restrict__ bl,
    float* __restrict__ out) {
  __shared__ float sO[L * EP];
  __shared__ float pmax[4][D];
  __shared__ float sP[D];
  __shared__ float part[8][LABELS];
  const int t = threadIdx.x;
  const int b = blockIdx.x;
  for (int i = t * 4; i < L * D; i += 512 * 4) {
    int r = i >> 7, c = i & 127;
    float4 v = *(const float4*)&ob[(size_t)(b * L + r) * D + c];
    float* p = &sO[r * EP + c];
    p[0] = v.x; p[1] = v.y; p[2] = v.z; p[3] = v.w;
  }
  __syncthreads();
  const int rg = t >> 5;
  const int cg = t & 31;
  const int r0 = rg * 4, c0 = cg * 4;
  float acc[4][4] = {};
#pragma unroll 4
  for (int k = 0; k < D; ++k) {
    float4 w = *(const float4*)&Wo[k * D + c0];
    float e0 = sO[(r0 + 0) * EP + k];
    float e1 = sO[(r0 + 1) * EP + k];
    float e2 = sO[(r0 + 2) * EP + k];
    float e3 = sO[(r0 + 3) * EP + k];
    acc[0][0] += e0 * w.x; acc[0][1] += e0 * w.y; acc[0][2] += e0 * w.z; acc[0][3] += e0 * w.w;
    acc[1][0] += e1 * w.x; acc[1][1] += e1 * w.y; acc[1][2] += e1 * w.z; acc[1][3] += e1 * w.w;
    acc[2][0] += e2 * w.x; acc[2][1] += e2 * w.y; acc[2][2] += e2 * w.z; acc[2][3] += e2 * w.w;
    acc[3][0] += e3 * w.x; acc[3][1] += e3 * w.y; acc[3][2] += e3 * w.z; acc[3][3] += e3 * w.w;
  }
  __syncthreads();
#pragma unroll
  for (int i = 0; i < 4; ++i) {
    float4 o = make_float4(acc[i][0], acc[i][1], acc[i][2], acc[i][3]);
    *(float4*)&sO[(r0 + i) * EP + c0] = o;
  }
  __syncthreads();
  {
    const int d = t & 127;
    const int grp = t >> 7;
    float m = -1e30f;
    for (int r = grp; r < L; r += 4) m = fmaxf(m, sO[r * EP + d]);
    pmax[grp][d] = m;
  }
  __syncthreads();
  if (t < 128) {
    sP[t] = fmaxf(fmaxf(pmax[0][t], pmax[1][t]), fmaxf(pmax[2][t], pmax[3][t]));
  }
  __syncthreads();
  if (t < 8 * LABELS) {
    const int grp = t / LABELS;
    const int lab = t % LABELS;
    float a = 0.f;
#pragma unroll
    for (int j = 0; j < 16; ++j) {
      int d = grp * 16 + j;
      a += sP[d] * Wl[d * LABELS + lab];
    }
    part[grp][lab] = a;
  }
  __syncthreads();
  if (t < LABELS) {
    float a = bl[t];
#pragma unroll
    for (int g = 0; g < 8; ++g) a += part[g][t];
    out[b * LABELS + t] = a;
  }
}

extern "C" void kernel_launch(void* const* d_in, const int* in_sizes, int n_in,
                              void* d_out, int out_size, void* d_ws, size_t ws_size,
                              hipStream_t stream) {
  const int* tokens = (const int*)d_in[0];
  const int* mask = (const int*)d_in[1];
  const float* emb = (const float*)d_in[2];
  const float* Wc = (const float*)d_in[3];
  const float* bc = (const float*)d_in[4];
  const float* Wq = (const float*)d_in[5];
  const float* Wk = (const float*)d_in[6];
  const float* Wv = (const float*)d_in[7];
  const float* Wo = (const float*)d_in[8];
  const float* Wl = (const float*)d_in[9];
  const float* bl = (const float*)d_in[10];
  float* out = (float*)d_out;

  __hip_bfloat16* T = (__hip_bfloat16*)d_ws;        // VOCAB*D bf16 = 7.68 MB
  float* qb = (float*)(T + (size_t)VOCAB * D);      // B*L*D f32 each
  float* kb = qb + (size_t)B * L * D;
  float* vb = kb + (size_t)B * L * D;
  float* obuf = vb + (size_t)B * L * D;

  hipLaunchKernelGGL(k0_embWc, dim3((VOCAB + 63) / 64), dim3(256), 0, stream,
                     emb, Wc, bc, T);
  hipLaunchKernelGGL(k1_tree_qkv, dim3(B * L / 8), dim3(512), 0, stream,
                     tokens, T, Wq, Wk, Wv, qb, kb, vb);
  hipLaunchKernelGGL(k2_attn, dim3(B * SPLIT), dim3(512), 0, stream,
                     qb, kb, vb, mask, obuf);
  hipLaunchKernelGGL(k23_proj_pool, dim3(B), dim3(512), 0, stream,
                     obuf, Wo, Wl, bl, out);
}

// Round 9
// 77.033 us; speedup vs baseline: 1.3706x; 1.3706x over previous
//
#include <hip/hip_runtime.h>
#include <hip/hip_bf16.h>
#include <math.h>

#define B 64
#define L 64
#define NPT 127
#define D 128
#define VOCAB 30000
#define LABELS 30
#define SPLIT 4
#define KP 132    // padded LDS row stride (floats) for K/V tiles in k2 (16B-aligned)
#define EP 132    // padded row stride for k23 tile
#define WCS 136   // wcT row stride in ushorts (272B: 16B-aligned)

typedef __attribute__((ext_vector_type(8))) short bf16x8;
typedef __attribute__((ext_vector_type(4))) float f32x4;

__device__ __forceinline__ float bfhi(unsigned int u) {
  unsigned int x = u & 0xffff0000u;
  return __builtin_bit_cast(float, x);
}
__device__ __forceinline__ float bflo(unsigned int u) {
  unsigned int x = u << 16;
  return __builtin_bit_cast(float, x);
}
__device__ __forceinline__ unsigned short f2bf(float f) {
  __hip_bfloat16 h = __float2bfloat16(f);  // RNE
  return __builtin_bit_cast(unsigned short, h);
}

// ---------------------------------------------------------------------------
// K0 (MFMA): T[v][e] = bf16( sum_d emb[v][d]*Wc[d][e] + bc[e] )
// Wc^T staged in LDS bf16 with coalesced global reads (R7 fix kept).
// ---------------------------------------------------------------------------
__global__ __launch_bounds__(256) void k0_embWc(const float* __restrict__ emb,
                                                const float* __restrict__ Wc,
                                                const float* __restrict__ bc,
                                                __hip_bfloat16* __restrict__ T) {
  __shared__ unsigned short wcT[D * WCS];  // Wc^T bf16: wcT[e*WCS + d], ~34KB
  const int t = threadIdx.x;
  for (int i = t; i < D * D / 4; i += 256) {
    const int d = i >> 5;            // row of Wc
    const int e0 = (i & 31) * 4;     // 4 consecutive cols (lane-fast)
    float4 wv = *(const float4*)&Wc[d * D + e0];
    wcT[(e0 + 0) * WCS + d] = f2bf(wv.x);
    wcT[(e0 + 1) * WCS + d] = f2bf(wv.y);
    wcT[(e0 + 2) * WCS + d] = f2bf(wv.z);
    wcT[(e0 + 3) * WCS + d] = f2bf(wv.w);
  }
  __syncthreads();
  const int w = t >> 6, lane = t & 63;
  const int m = lane & 15;       // A-row / B-col within tile
  const int kg = lane >> 4;      // k-group 0..3
  int arow = blockIdx.x * 64 + w * 16 + m;
  if (arow >= VOCAB) arow = VOCAB - 1;  // clamp reads; stores guarded below
  const float* ap = emb + (size_t)arow * D + kg * 8;
  bf16x8 afrag[4];
#pragma unroll
  for (int kc = 0; kc < 4; ++kc) {
    float4 lo = *(const float4*)(ap + kc * 32);
    float4 hi = *(const float4*)(ap + kc * 32 + 4);
    union { bf16x8 v; unsigned short s[8]; } u;
    u.s[0] = f2bf(lo.x); u.s[1] = f2bf(lo.y); u.s[2] = f2bf(lo.z); u.s[3] = f2bf(lo.w);
    u.s[4] = f2bf(hi.x); u.s[5] = f2bf(hi.y); u.s[6] = f2bf(hi.z); u.s[7] = f2bf(hi.w);
    afrag[kc] = u.v;
  }
  const int grow0 = blockIdx.x * 64 + w * 16 + kg * 4;
#pragma unroll
  for (int ct = 0; ct < 8; ++ct) {
    const int col = ct * 16 + m;
    f32x4 acc = {0.f, 0.f, 0.f, 0.f};
#pragma unroll
    for (int kc = 0; kc < 4; ++kc) {
      bf16x8 bfrag = *(const bf16x8*)&wcT[col * WCS + kc * 32 + kg * 8];
      acc = __builtin_amdgcn_mfma_f32_16x16x32_bf16(afrag[kc], bfrag, acc, 0, 0, 0);
    }
    const float bcv = bc[col];
#pragma unroll
    for (int r = 0; r < 4; ++r) {
      const int grow = grow0 + r;
      if (grow < VOCAB)
        T[(size_t)grow * D + col] = __float2bfloat16(acc[r] + bcv);
    }
  }
}

// ---------------------------------------------------------------------------
// K1a: tree-encode, one WAVE per (b,l) row; 8 rows per 512-thread block.
// Tokens via wave-uniform SCALAR loads (no LDS round-trip in the address
// chain). Post-order streaming subtree-sum in a 6-deep register stack.
// ---------------------------------------------------------------------------
__global__ __launch_bounds__(512) void k1a_tree(
    const int* __restrict__ tokens, const __hip_bfloat16* __restrict__ T,
    float* __restrict__ enc) {
  const int t = threadIdx.x;
  const int w = __builtin_amdgcn_readfirstlane(t >> 6);  // wave id, SGPR
  const int lane = t & 63;
  const int row = blockIdx.x * 8 + w;                    // wave-uniform
  const int* __restrict__ tokrow = tokens + (size_t)row * NPT;
  const unsigned* Tp = (const unsigned*)T;  // one u32 = dim pair; row = 64 u32
  float m0 = -1e30f, m1 = -1e30f;
  float stk0[6], stk1[6];
#pragma unroll
  for (int li = 0; li < 64; ++li) {
    int tokl = tokrow[63 + li];               // scalar load (uniform addr)
    unsigned u = Tp[(size_t)tokl * 64 + lane];
    float cur0 = bflo(u), cur1 = bfhi(u);
    m0 = fmaxf(m0, cur0);
    m1 = fmaxf(m1, cur1);
    int x = li;
#pragma unroll
    for (int h = 0; h < 6; ++h) {
      if (!(x & 1)) break;
      int pn = ((64 + li) >> (h + 1)) - 1;
      int tokp = tokrow[pn];                  // scalar load (uniform addr)
      unsigned up = Tp[(size_t)tokp * 64 + lane];
      cur0 = stk0[h] + cur0 + bflo(up);
      cur1 = stk1[h] + cur1 + bfhi(up);
      m0 = fmaxf(m0, cur0);
      m1 = fmaxf(m1, cur1);
      x >>= 1;
    }
    if (li != 63) {
      int h2 = 0, y = li;
      while (y & 1) { ++h2; y >>= 1; }
      stk0[h2] = cur0;
      stk1[h2] = cur1;
    }
  }
  float2 o = make_float2(fmaxf(m0, 0.0f), fmaxf(m1, 0.0f));
  *(float2*)&enc[(size_t)row * D + 2 * lane] = o;
}

// ---------------------------------------------------------------------------
// K1b: q/k/v projection GEMM. enc(4096x128) @ W(128x128) for Wq/Wk/Wv.
// ---------------------------------------------------------------------------
__global__ __launch_bounds__(256) void k1b_qkv(
    const float* __restrict__ enc, const float* __restrict__ Wq,
    const float* __restrict__ Wk, const float* __restrict__ Wv,
    float* __restrict__ qb, float* __restrict__ kb, float* __restrict__ vb) {
  __shared__ float sE[32 * D];  // 16 KB
  const int t = threadIdx.x;
  const int rb = blockIdx.x / 3;
  const int cb = blockIdx.x % 3;
  const int r0 = rb * 32;
  const float* W = cb == 0 ? Wq : (cb == 1 ? Wk : Wv);
  float* outb = cb == 0 ? qb : (cb == 1 ? kb : vb);
  {
    const float4* E4 = (const float4*)(enc + (size_t)r0 * D);
    float4* sE4 = (float4*)sE;
#pragma unroll
    for (int i = 0; i < 4; ++i) sE4[t + 256 * i] = E4[t + 256 * i];
  }
  __syncthreads();
  const int rg = t >> 5;
  const int cg = t & 31;
  float acc[4][4] = {};
#pragma unroll 4
  for (int k = 0; k < D; ++k) {
    float4 w = *(const float4*)&W[k * D + cg * 4];
    float e0 = sE[(rg * 4 + 0) * D + k];
    float e1 = sE[(rg * 4 + 1) * D + k];
    float e2 = sE[(rg * 4 + 2) * D + k];
    float e3 = sE[(rg * 4 + 3) * D + k];
    acc[0][0] += e0 * w.x; acc[0][1] += e0 * w.y; acc[0][2] += e0 * w.z; acc[0][3] += e0 * w.w;
    acc[1][0] += e1 * w.x; acc[1][1] += e1 * w.y; acc[1][2] += e1 * w.z; acc[1][3] += e1 * w.w;
    acc[2][0] += e2 * w.x; acc[2][1] += e2 * w.y; acc[2][2] += e2 * w.z; acc[2][3] += e2 * w.w;
    acc[3][0] += e3 * w.x; acc[3][1] += e3 * w.y; acc[3][2] += e3 * w.z; acc[3][3] += e3 * w.w;
  }
#pragma unroll
  for (int i = 0; i < 4; ++i) {
    float4 o = make_float4(acc[i][0], acc[i][1], acc[i][2], acc[i][3]);
    *(float4*)&outb[(size_t)(r0 + rg * 4 + i) * D + cg * 4] = o;
  }
}

// ---------------------------------------------------------------------------
// K2: attention for one (batch, split of 16 q-rows). Writes pre-Wo rows.
// ---------------------------------------------------------------------------
__global__ __launch_bounds__(512) void k2_attn(
    const float* __restrict__ qb, const float* __restrict__ kb,
    const float* __restrict__ vb, const int* __restrict__ mask,
    float* __restrict__ ob) {
  __shared__ float sK[L * KP];
  __shared__ float sV[L * KP];
  __shared__ float sQ[8][D];
  const int t = threadIdx.x;
  const int w = t >> 6, lane = t & 63;
  const int b = blockIdx.x / SPLIT;
  const int sp = blockIdx.x % SPLIT;
  for (int i = t * 4; i < L * D; i += 512 * 4) {
    int r = i >> 7, c = i & 127;
    float4 kv = *(const float4*)&kb[(size_t)(b * L + r) * D + c];
    float4 vv = *(const float4*)&vb[(size_t)(b * L + r) * D + c];
    *(float4*)&sK[r * KP + c] = kv;
    *(float4*)&sV[r * KP + c] = vv;
  }
  __syncthreads();
#pragma unroll
  for (int it = 0; it < 2; ++it) {
    const int r = sp * 16 + w * 2 + it;
    float2 qv = *(const float2*)&qb[(size_t)(b * L + r) * D + lane * 2];
    sQ[w][lane * 2] = qv.x;
    sQ[w][lane * 2 + 1] = qv.y;
    float sc = 0.f;
    const float4* kr = (const float4*)&sK[lane * KP];
    const float4* qr = (const float4*)&sQ[w][0];
#pragma unroll 8
    for (int k4 = 0; k4 < 32; ++k4) {
      float4 kv = kr[k4];
      float4 q4 = qr[k4];
      sc += q4.x * kv.x + q4.y * kv.y + q4.z * kv.z + q4.w * kv.w;
    }
    sc *= 0.08838834764831845f;
    if (mask[((size_t)b * L + r) * L + lane] <= 0) sc = -1e9f;
    float mx = sc;
#pragma unroll
    for (int off = 32; off >= 1; off >>= 1) mx = fmaxf(mx, __shfl_xor(mx, off));
    float ex = __expf(sc - mx);
    float sm = ex;
#pragma unroll
    for (int off = 32; off >= 1; off >>= 1) sm += __shfl_xor(sm, off);
    float a = ex / sm;
    float o0 = 0.f, o1 = 0.f;
#pragma unroll
    for (int j = 0; j < L; ++j) {
      float aj = __shfl(a, j);
      o0 += aj * sV[j * KP + lane];
      o1 += aj * sV[j * KP + lane + 64];
    }
    ob[(size_t)(b * L + r) * D + lane] = o0;
    ob[(size_t)(b * L + r) * D + lane + 64] = o1;
  }
}

// ---------------------------------------------------------------------------
// K23: per batch (64 blocks, 512 threads): out2 = ob@Wo in LDS,
// pooled max over rows, logits -> out.
// ---------------------------------------------------------------------------
__global__ __launch_bounds__(512) void k23_proj_pool(
    const float* __restrict__ ob, const float* __restrict__ Wo,
    const float* __restrict__ Wl, const float* __restrict__ bl,
    float* __restrict__ out) {
  __shared__ float sO[L * EP];
  __shared__ float pmax[4][D];
  __shared__ float sP[D];
  __shared__ float part[8][LABELS];
  const int t = threadIdx.x;
  const int b = blockIdx.x;
  for (int i = t * 4; i < L * D; i += 512 * 4) {
    int r = i >> 7, c = i & 127;
    float4 v = *(const float4*)&ob[(size_t)(b * L + r) * D + c];
    float* p = &sO[r * EP + c];
    p[0] = v.x; p[1] = v.y; p[2] = v.z; p[3] = v.w;
  }
  __syncthreads();
  const int rg = t >> 5;
  const int cg = t & 31;
  const int r0 = rg * 4, c0 = cg * 4;
  float acc[4][4] = {};
#pragma unroll 4
  for (int k = 0; k < D; ++k) {
    float4 w = *(const float4*)&Wo[k * D + c0];
    float e0 = sO[(r0 + 0) * EP + k];
    float e1 = sO[(r0 + 1) * EP + k];
    float e2 = sO[(r0 + 2) * EP + k];
    float e3 = sO[(r0 + 3) * EP + k];
    acc[0][0] += e0 * w.x; acc[0][1] += e0 * w.y; acc[0][2] += e0 * w.z; acc[0][3] += e0 * w.w;
    acc[1][0] += e1 * w.x; acc[1][1] += e1 * w.y; acc[1][2] += e1 * w.z; acc[1][3] += e1 * w.w;
    acc[2][0] += e2 * w.x; acc[2][1] += e2 * w.y; acc[2][2] += e2 * w.z; acc[2][3] += e2 * w.w;
    acc[3][0] += e3 * w.x; acc[3][1] += e3 * w.y; acc[3][2] += e3 * w.z; acc[3][3] += e3 * w.w;
  }
  __syncthreads();
#pragma unroll
  for (int i = 0; i < 4; ++i) {
    float4 o = make_float4(acc[i][0], acc[i][1], acc[i][2], acc[i][3]);
    *(float4*)&sO[(r0 + i) * EP + c0] = o;
  }
  __syncthreads();
  {
    const int d = t & 127;
    const int grp = t >> 7;
    float m = -1e30f;
    for (int r = grp; r < L; r += 4) m = fmaxf(m, sO[r * EP + d]);
    pmax[grp][d] = m;
  }
  __syncthreads();
  if (t < 128) {
    sP[t] = fmaxf(fmaxf(pmax[0][t], pmax[1][t]), fmaxf(pmax[2][t], pmax[3][t]));
  }
  __syncthreads();
  if (t < 8 * LABELS) {
    const int grp = t / LABELS;
    const int lab = t % LABELS;
    float a = 0.f;
#pragma unroll
    for (int j = 0; j < 16; ++j) {
      int d = grp * 16 + j;
      a += sP[d] * Wl[d * LABELS + lab];
    }
    part[grp][lab] = a;
  }
  __syncthreads();
  if (t < LABELS) {
    float a = bl[t];
#pragma unroll
    for (int g = 0; g < 8; ++g) a += part[g][t];
    out[b * LABELS + t] = a;
  }
}

extern "C" void kernel_launch(void* const* d_in, const int* in_sizes, int n_in,
                              void* d_out, int out_size, void* d_ws, size_t ws_size,
                              hipStream_t stream) {
  const int* tokens = (const int*)d_in[0];
  const int* mask = (const int*)d_in[1];
  const float* emb = (const float*)d_in[2];
  const float* Wc = (const float*)d_in[3];
  const float* bc = (const float*)d_in[4];
  const float* Wq = (const float*)d_in[5];
  const float* Wk = (const float*)d_in[6];
  const float* Wv = (const float*)d_in[7];
  const float* Wo = (const float*)d_in[8];
  const float* Wl = (const float*)d_in[9];
  const float* bl = (const float*)d_in[10];
  float* out = (float*)d_out;

  __hip_bfloat16* T = (__hip_bfloat16*)d_ws;        // VOCAB*D bf16 = 7.68 MB
  float* enc = (float*)(T + (size_t)VOCAB * D);     // B*L*D f32 each
  float* qb = enc + (size_t)B * L * D;
  float* kb = qb + (size_t)B * L * D;
  float* vb = kb + (size_t)B * L * D;
  float* obuf = vb + (size_t)B * L * D;

  hipLaunchKernelGGL(k0_embWc, dim3((VOCAB + 63) / 64), dim3(256), 0, stream,
                     emb, Wc, bc, T);
  hipLaunchKernelGGL(k1a_tree, dim3(B * L / 8), dim3(512), 0, stream,
                     tokens, T, enc);
  hipLaunchKernelGGL(k1b_qkv, dim3((B * L / 32) * 3), dim3(256), 0, stream,
                     enc, Wq, Wk, Wv, qb, kb, vb);
  hipLaunchKernelGGL(k2_attn, dim3(B * SPLIT), dim3(512), 0, stream,
                     qb, kb, vb, mask, obuf);
  hipLaunchKernelGGL(k23_proj_pool, dim3(B), dim3(512), 0, stream,
                     obuf, Wo, Wl, bl, out);
}

// Round 10
// 74.797 us; speedup vs baseline: 1.4116x; 1.0299x over previous
//
#include <hip/hip_runtime.h>
#include <hip/hip_bf16.h>
#include <math.h>

#define B 64
#define L 64
#define NPT 127
#define D 128
#define VOCAB 30000
#define LABELS 30
#define SPLIT 4
#define KP 132    // padded LDS row stride (floats) for K/V tiles in k2 (16B-aligned)
#define WCS 136   // wcT row stride in ushorts (272B: 16B-aligned)

typedef __attribute__((ext_vector_type(8))) short bf16x8;
typedef __attribute__((ext_vector_type(4))) float f32x4;

__device__ __forceinline__ float bfhi(unsigned int u) {
  unsigned int x = u & 0xffff0000u;
  return __builtin_bit_cast(float, x);
}
__device__ __forceinline__ float bflo(unsigned int u) {
  unsigned int x = u << 16;
  return __builtin_bit_cast(float, x);
}
__device__ __forceinline__ unsigned short f2bf(float f) {
  __hip_bfloat16 h = __float2bfloat16(f);  // RNE
  return __builtin_bit_cast(unsigned short, h);
}

// ---------------------------------------------------------------------------
// K0 (MFMA): T[v][e] = bf16( sum_d emb[v][d]*Wc[d][e] + bc[e] )
// ---------------------------------------------------------------------------
__global__ __launch_bounds__(256) void k0_embWc(const float* __restrict__ emb,
                                                const float* __restrict__ Wc,
                                                const float* __restrict__ bc,
                                                __hip_bfloat16* __restrict__ T) {
  __shared__ unsigned short wcT[D * WCS];  // Wc^T bf16: wcT[e*WCS + d], ~34KB
  const int t = threadIdx.x;
  for (int i = t; i < D * D / 4; i += 256) {
    const int d = i >> 5;            // row of Wc
    const int e0 = (i & 31) * 4;     // 4 consecutive cols (lane-fast)
    float4 wv = *(const float4*)&Wc[d * D + e0];
    wcT[(e0 + 0) * WCS + d] = f2bf(wv.x);
    wcT[(e0 + 1) * WCS + d] = f2bf(wv.y);
    wcT[(e0 + 2) * WCS + d] = f2bf(wv.z);
    wcT[(e0 + 3) * WCS + d] = f2bf(wv.w);
  }
  __syncthreads();
  const int w = t >> 6, lane = t & 63;
  const int m = lane & 15;       // A-row / B-col within tile
  const int kg = lane >> 4;      // k-group 0..3
  int arow = blockIdx.x * 64 + w * 16 + m;
  if (arow >= VOCAB) arow = VOCAB - 1;  // clamp reads; stores guarded below
  const float* ap = emb + (size_t)arow * D + kg * 8;
  bf16x8 afrag[4];
#pragma unroll
  for (int kc = 0; kc < 4; ++kc) {
    float4 lo = *(const float4*)(ap + kc * 32);
    float4 hi = *(const float4*)(ap + kc * 32 + 4);
    union { bf16x8 v; unsigned short s[8]; } u;
    u.s[0] = f2bf(lo.x); u.s[1] = f2bf(lo.y); u.s[2] = f2bf(lo.z); u.s[3] = f2bf(lo.w);
    u.s[4] = f2bf(hi.x); u.s[5] = f2bf(hi.y); u.s[6] = f2bf(hi.z); u.s[7] = f2bf(hi.w);
    afrag[kc] = u.v;
  }
  const int grow0 = blockIdx.x * 64 + w * 16 + kg * 4;
#pragma unroll
  for (int ct = 0; ct < 8; ++ct) {
    const int col = ct * 16 + m;
    f32x4 acc = {0.f, 0.f, 0.f, 0.f};
#pragma unroll
    for (int kc = 0; kc < 4; ++kc) {
      bf16x8 bfrag = *(const bf16x8*)&wcT[col * WCS + kc * 32 + kg * 8];
      acc = __builtin_amdgcn_mfma_f32_16x16x32_bf16(afrag[kc], bfrag, acc, 0, 0, 0);
    }
    const float bcv = bc[col];
#pragma unroll
    for (int r = 0; r < 4; ++r) {
      const int grow = grow0 + r;
      if (grow < VOCAB)
        T[(size_t)grow * D + col] = __float2bfloat16(acc[r] + bcv);
    }
  }
}

// ---------------------------------------------------------------------------
// K1 (fused tree + qkv): phase 1 = one WAVE per (b,l) row, scalar token
// loads, register-stack streaming subtree-sum -> sEnc LDS. phase 2 = thread
// t<384 -> (matrix t>>7, col t&127): COALESCED W[k*D+c] wave-loads, sEnc
// broadcasts, 8 rows per thread. W read once per block from L2.
// ---------------------------------------------------------------------------
__global__ __launch_bounds__(512) void k1_tree_qkv(
    const int* __restrict__ tokens, const __hip_bfloat16* __restrict__ T,
    const float* __restrict__ Wq, const float* __restrict__ Wk,
    const float* __restrict__ Wv, float* __restrict__ qb,
    float* __restrict__ kb, float* __restrict__ vb) {
  __shared__ float sEnc[8][D];
  const int t = threadIdx.x;
  const int w = __builtin_amdgcn_readfirstlane(t >> 6);  // wave id, SGPR
  const int lane = t & 63;
  const int row = blockIdx.x * 8 + w;                    // wave-uniform
  const int* __restrict__ tokrow = tokens + (size_t)row * NPT;
  const unsigned* Tp = (const unsigned*)T;  // one u32 = dim pair; row = 64 u32
  float m0 = -1e30f, m1 = -1e30f;
  float stk0[6], stk1[6];
#pragma unroll
  for (int li = 0; li < 64; ++li) {
    int tokl = tokrow[63 + li];               // scalar load (uniform addr)
    unsigned u = Tp[(size_t)tokl * 64 + lane];
    float cur0 = bflo(u), cur1 = bfhi(u);
    m0 = fmaxf(m0, cur0);
    m1 = fmaxf(m1, cur1);
    int x = li;
#pragma unroll
    for (int h = 0; h < 6; ++h) {
      if (!(x & 1)) break;
      int pn = ((64 + li) >> (h + 1)) - 1;
      int tokp = tokrow[pn];                  // scalar load (uniform addr)
      unsigned up = Tp[(size_t)tokp * 64 + lane];
      cur0 = stk0[h] + cur0 + bflo(up);
      cur1 = stk1[h] + cur1 + bfhi(up);
      m0 = fmaxf(m0, cur0);
      m1 = fmaxf(m1, cur1);
      x >>= 1;
    }
    if (li != 63) {
      int h2 = 0, y = li;
      while (y & 1) { ++h2; y >>= 1; }
      stk0[h2] = cur0;
      stk1[h2] = cur1;
    }
  }
  sEnc[w][2 * lane] = fmaxf(m0, 0.0f);
  sEnc[w][2 * lane + 1] = fmaxf(m1, 0.0f);
  __syncthreads();
  if (t < 384) {
    const int mi = t >> 7;        // 0=q, 1=k, 2=v
    const int c = t & 127;
    const float* W = mi == 0 ? Wq : (mi == 1 ? Wk : Wv);
    float* outb = mi == 0 ? qb : (mi == 1 ? kb : vb);
    float acc[8] = {};
#pragma unroll 8
    for (int k = 0; k < D; ++k) {
      float wv = W[k * D + c];    // coalesced across 128 lanes
#pragma unroll
      for (int r = 0; r < 8; ++r) acc[r] += sEnc[r][k] * wv;  // broadcasts
    }
    const int row0 = blockIdx.x * 8;
#pragma unroll
    for (int r = 0; r < 8; ++r)
      outb[(size_t)(row0 + r) * D + c] = acc[r];
  }
}

// ---------------------------------------------------------------------------
// K2 (fused attn + Wo-proj + partial pool): one (batch, split of 16 q-rows)
// per block. Attention rows -> sOr LDS; proj with coalesced Wo loads;
// block writes 16-row pooled max to pool[b*SPLIT+sp].
// ---------------------------------------------------------------------------
__global__ __launch_bounds__(512) void k2_attn_proj(
    const float* __restrict__ qb, const float* __restrict__ kb,
    const float* __restrict__ vb, const int* __restrict__ mask,
    const float* __restrict__ Wo, float* __restrict__ pool) {
  __shared__ float sK[L * KP];      // 33.8 KB
  __shared__ float sV[L * KP];      // 33.8 KB
  __shared__ float sQ[8][D];        // 4 KB
  __shared__ float sOr[16][D];      // 8 KB
  __shared__ float pmax[4][D];      // 2 KB
  const int t = threadIdx.x;
  const int w = t >> 6, lane = t & 63;
  const int b = blockIdx.x / SPLIT;
  const int sp = blockIdx.x % SPLIT;
  for (int i = t * 4; i < L * D; i += 512 * 4) {
    int r = i >> 7, c = i & 127;
    float4 kv = *(const float4*)&kb[(size_t)(b * L + r) * D + c];
    float4 vv = *(const float4*)&vb[(size_t)(b * L + r) * D + c];
    *(float4*)&sK[r * KP + c] = kv;
    *(float4*)&sV[r * KP + c] = vv;
  }
  __syncthreads();
#pragma unroll
  for (int it = 0; it < 2; ++it) {
    const int r = sp * 16 + w * 2 + it;
    float2 qv = *(const float2*)&qb[(size_t)(b * L + r) * D + lane * 2];
    sQ[w][lane * 2] = qv.x;
    sQ[w][lane * 2 + 1] = qv.y;
    float sc = 0.f;
    const float4* kr = (const float4*)&sK[lane * KP];
    const float4* qr = (const float4*)&sQ[w][0];
#pragma unroll 8
    for (int k4 = 0; k4 < 32; ++k4) {
      float4 kv = kr[k4];
      float4 q4 = qr[k4];
      sc += q4.x * kv.x + q4.y * kv.y + q4.z * kv.z + q4.w * kv.w;
    }
    sc *= 0.08838834764831845f;
    if (mask[((size_t)b * L + r) * L + lane] <= 0) sc = -1e9f;
    float mx = sc;
#pragma unroll
    for (int off = 32; off >= 1; off >>= 1) mx = fmaxf(mx, __shfl_xor(mx, off));
    float ex = __expf(sc - mx);
    float sm = ex;
#pragma unroll
    for (int off = 32; off >= 1; off >>= 1) sm += __shfl_xor(sm, off);
    float a = ex / sm;
    float o0 = 0.f, o1 = 0.f;
#pragma unroll
    for (int j = 0; j < L; ++j) {
      float aj = __shfl(a, j);
      o0 += aj * sV[j * KP + lane];
      o1 += aj * sV[j * KP + lane + 64];
    }
    sOr[w * 2 + it][lane] = o0;
    sOr[w * 2 + it][lane + 64] = o1;
  }
  __syncthreads();
  // Wo projection: thread -> (col c, row group rg of 4 rows); coalesced Wo.
  {
    const int c = t & 127;
    const int rg = t >> 7;  // 0..3
    float acc[4] = {};
#pragma unroll 4
    for (int k = 0; k < D; ++k) {
      float wv = Wo[k * D + c];   // coalesced across 128 lanes
#pragma unroll
      for (int r = 0; r < 4; ++r) acc[r] += sOr[rg * 4 + r][k] * wv;
    }
    float pm = fmaxf(fmaxf(acc[0], acc[1]), fmaxf(acc[2], acc[3]));
    pmax[rg][c] = pm;
  }
  __syncthreads();
  if (t < 128) {
    float pv = fmaxf(fmaxf(pmax[0][t], pmax[1][t]), fmaxf(pmax[2][t], pmax[3][t]));
    pool[(size_t)blockIdx.x * D + t] = pv;
  }
}

// ---------------------------------------------------------------------------
// K3: final pooled max over splits + logits
// ---------------------------------------------------------------------------
__global__ __launch_bounds__(128) void k3_logits(const float* __restrict__ pool,
                                                 const float* __restrict__ Wl,
                                                 const float* __restrict__ bl,
                                                 float* __restrict__ out) {
  __shared__ float sP[D];
  const int b = blockIdx.x, t = threadIdx.x;
  float pv = pool[((size_t)b * SPLIT) * D + t];
#pragma unroll
  for (int i = 1; i < SPLIT; ++i)
    pv = fmaxf(pv, pool[((size_t)b * SPLIT + i) * D + t]);
  sP[t] = pv;
  __syncthreads();
  if (t < LABELS) {
    float a = bl[t];
#pragma unroll 4
    for (int d = 0; d < D; ++d) a += sP[d] * Wl[d * LABELS + t];
    out[b * LABELS + t] = a;
  }
}

extern "C" void kernel_launch(void* const* d_in, const int* in_sizes, int n_in,
                              void* d_out, int out_size, void* d_ws, size_t ws_size,
                              hipStream_t stream) {
  const int* tokens = (const int*)d_in[0];
  const int* mask = (const int*)d_in[1];
  const float* emb = (const float*)d_in[2];
  const float* Wc = (const float*)d_in[3];
  const float* bc = (const float*)d_in[4];
  const float* Wq = (const float*)d_in[5];
  const float* Wk = (const float*)d_in[6];
  const float* Wv = (const float*)d_in[7];
  const float* Wo = (const float*)d_in[8];
  const float* Wl = (const float*)d_in[9];
  const float* bl = (const float*)d_in[10];
  float* out = (float*)d_out;

  __hip_bfloat16* T = (__hip_bfloat16*)d_ws;        // VOCAB*D bf16 = 7.68 MB
  float* qb = (float*)(T + (size_t)VOCAB * D);      // B*L*D f32 each
  float* kb = qb + (size_t)B * L * D;
  float* vb = kb + (size_t)B * L * D;
  float* pool = vb + (size_t)B * L * D;             // B*SPLIT*D

  hipLaunchKernelGGL(k0_embWc, dim3((VOCAB + 63) / 64), dim3(256), 0, stream,
                     emb, Wc, bc, T);
  hipLaunchKernelGGL(k1_tree_qkv, dim3(B * L / 8), dim3(512), 0, stream,
                     tokens, T, Wq, Wk, Wv, qb, kb, vb);
  hipLaunchKernelGGL(k2_attn_proj, dim3(B * SPLIT), dim3(512), 0, stream,
                     qb, kb, vb, mask, Wo, pool);
  hipLaunchKernelGGL(k3_logits, dim3(B), dim3(128), 0, stream,
                     pool, Wl, bl, out);
}